// Round 5
// baseline (272.980 us; speedup 1.0000x reference)
//
#include <hip/hip_runtime.h>
#include <hip/hip_bf16.h>

#define NS   16384
#define FKD  2048
#define CD   100
#define CP   112
#define MT   64
#define EPSF 1e-8f
#define SFK  (FKD * CP)          // 229376 elements of one S partial
#define NGRP (NS / 8)            // 2048 k-groups of 8

typedef float f32x4 __attribute__((ext_vector_type(4)));
typedef short bf16x8 __attribute__((ext_vector_type(8)));

__device__ inline unsigned short f2bf(float f) {
    unsigned int u = __float_as_uint(f);
    u += 0x7FFFu + ((u >> 16) & 1u);   // RNE; inputs are finite in [0,1]
    return (unsigned short)(u >> 16);
}

// ---------------- prep: teacher -> bf16 fragment layout ----------------
// Bp[g][c][j] = bf16(tp[(8g+j)*CD + c]) ; col CD == 1.0 (bin-mass column), >CD == 0
__global__ __launch_bounds__(256) void ebl_prep(
    const float* __restrict__ tp, unsigned short* __restrict__ Bp)
{
    const int idx = blockIdx.x * 256 + threadIdx.x;     // (g, c)
    if (idx >= NGRP * CP) return;
    const int g = idx / CP, c = idx - g * CP;
    unsigned short v[8];
    if (c < CD) {
        const float* p = tp + (size_t)g * 8 * CD + c;
        #pragma unroll
        for (int j = 0; j < 8; ++j) v[j] = f2bf(p[(size_t)j * CD]);
    } else {
        const unsigned short fill = (c == CD) ? 0x3F80 : 0;   // bf16(1.0) / 0
        #pragma unroll
        for (int j = 0; j < 8; ++j) v[j] = fill;
    }
    *reinterpret_cast<uint4*>(Bp + (size_t)idx * 8) = *reinterpret_cast<const uint4*>(v);
}

// ---------------- GEMM: barrier-free; occupancy-max (8 waves/SIMD) ----------------
// S_partial[kc][m][c] (bf16) = sum over k-chunk of bf16(mem[n][m]) * Bp[n][c]
__global__ __launch_bounds__(256, 8) void ebl_gemm(
    const float* __restrict__ mem, const unsigned short* __restrict__ Bp,
    unsigned short* __restrict__ spart, int steps)
{
    const int t  = threadIdx.x;
    const int w  = t >> 6;                 // wave -> m-subtile
    const int l  = t & 63;
    const int lg = l >> 4, lr = l & 15;
    const int m  = blockIdx.x * MT + w * 16 + lr;
    const int kc = blockIdx.y;
    const int g0 = kc * steps * 4 + lg;    // this lane's first k-group

    const float*          ap = mem + (size_t)g0 * 8 * FKD + m;
    const unsigned short* bp = Bp + ((size_t)g0 * CP + lr) * 8;
    const size_t aStep = (size_t)32 * FKD;   // one k-phase = 32 n-rows
    const size_t bStep = (size_t)4 * CP * 8;

    f32x4 acc[7];
    #pragma unroll
    for (int i = 0; i < 7; ++i) acc[i] = (f32x4){0.f, 0.f, 0.f, 0.f};

    float a0[8], a1[8]; bf16x8 b0[7], b1[7];

#define LOADA(dst, base) { \
    const float* _p = (base); \
    _Pragma("unroll") \
    for (int j = 0; j < 8; ++j) dst[j] = _p[(size_t)j * FKD]; }
#define LOADB(dst, base) { \
    const unsigned short* _q = (base); \
    _Pragma("unroll") \
    for (int nt = 0; nt < 7; ++nt) dst[nt] = *reinterpret_cast<const bf16x8*>(_q + nt * 128); }
#define COMPUTE(aB, bB) { \
    bf16x8 af; \
    _Pragma("unroll") \
    for (int j = 0; j < 8; ++j) af[j] = (short)f2bf(aB[j]); \
    _Pragma("unroll") \
    for (int nt = 0; nt < 7; ++nt) \
        acc[nt] = __builtin_amdgcn_mfma_f32_16x16x32_bf16(af, bB[nt], acc[nt], 0, 0, 0); }

    LOADA(a0, ap);             LOADB(b0, bp);
    LOADA(a1, ap + aStep);     LOADB(b1, bp + bStep);

    // steps is even (8/16/32) by construction
    for (int s = 0; s < steps - 2; s += 2) {
        COMPUTE(a0, b0);
        LOADA(a0, ap + 2 * aStep);  LOADB(b0, bp + 2 * bStep);
        COMPUTE(a1, b1);
        LOADA(a1, ap + 3 * aStep);  LOADB(b1, bp + 3 * bStep);
        ap += 2 * aStep; bp += 2 * bStep;
    }
    COMPUTE(a0, b0);
    COMPUTE(a1, b1);

#undef LOADA
#undef LOADB
#undef COMPUTE

    // C/D layout: col = lane&15, row = (lane>>4)*4 + reg   [verified rounds 1-4]
    unsigned short* sp = spart + (size_t)kc * SFK;
    #pragma unroll
    for (int nt = 0; nt < 7; ++nt) {
        const int c = nt * 16 + lr;
        #pragma unroll
        for (int r = 0; r < 4; ++r) {
            const int mm = blockIdx.x * MT + w * 16 + lg * 4 + r;
            sp[(size_t)mm * CP + c] = f2bf(acc[nt][r]);
        }
    }
}

// ---------------- reduce split-K partials (bf16 -> fp32, parallel) ----------------
__global__ __launch_bounds__(256) void ebl_reduce(
    const unsigned short* __restrict__ spart, float* __restrict__ S, int NK)
{
    const int idx = blockIdx.x * 256 + threadIdx.x;   // uint (2-element) index
    if (idx >= SFK / 2) return;
    float s0 = 0.f, s1 = 0.f;
    for (int p = 0; p < NK; ++p) {
        const unsigned raw = *reinterpret_cast<const unsigned*>(spart + (size_t)p * SFK + (size_t)idx * 2);
        s0 += __uint_as_float(raw << 16);
        s1 += __uint_as_float(raw & 0xFFFF0000u);
    }
    *reinterpret_cast<float2*>(S + (size_t)idx * 2) = make_float2(s0, s1);
}

// ---------------- entropies per f, partial losses ----------------
__global__ __launch_bounds__(256) void ebl_entropy(
    const float* __restrict__ S, float* __restrict__ fpart)
{
    __shared__ float Ss[32 * CP];
    __shared__ float massL[32];
    __shared__ float red[4];
    const int t = threadIdx.x;
    const int f = blockIdx.x;

    for (int idx = t; idx < 32 * CP; idx += 256)
        Ss[idx] = S[(size_t)f * 32 * CP + idx];
    __syncthreads();
    if (t < 32) massL[t] = Ss[t * CP + CD] + EPSF;   // ones-column = bin mass (+EPS)
    __syncthreads();

    float a_int = 0.f, a_mix = 0.f;
    for (int idx = t; idx < 32 * CD; idx += 256) {
        const int k = idx / CD, c = idx - k * CD;
        const float cent = Ss[k * CP + c] / massL[k];
        a_int -= cent * logf(cent + EPSF) * massL[k];
    }
    for (int idx = t; idx < 31 * CD; idx += 256) {
        const int k = idx / CD, c = idx - k * CD;
        const float mix = 0.5f * (Ss[k * CP + c] / massL[k] + Ss[(k + 1) * CP + c] / massL[k + 1]);
        a_mix += mix * logf(mix + EPSF);
    }

    float part = a_int * (1.0f / (float)NS) + 0.5f * a_mix;
    #pragma unroll
    for (int off = 32; off > 0; off >>= 1) part += __shfl_down(part, off);
    if ((t & 63) == 0) red[t >> 6] = part;
    __syncthreads();
    if (t == 0) fpart[f] = (red[0] + red[1]) + (red[2] + red[3]);
}

__global__ void ebl_finalize(const float* __restrict__ fpart, float* __restrict__ out) {
    float v = fpart[threadIdx.x];
    #pragma unroll
    for (int off = 32; off > 0; off >>= 1) v += __shfl_down(v, off);
    if (threadIdx.x == 0) out[0] = v;
}

extern "C" void kernel_launch(void* const* d_in, const int* in_sizes, int n_in,
                              void* d_out, int out_size, void* d_ws, size_t ws_size,
                              hipStream_t stream)
{
    const float* mem = (const float*)d_in[0];
    const float* tp  = (const float*)d_in[1];
    float* out = (float*)d_out;

    const size_t bpBytes = (size_t)NGRP * CP * 8 * 2;    // 3,670,016 B (16-aligned)

    int NK = 64;
    while (NK > 1 &&
           bpBytes + (size_t)NK * SFK * 2 + ((size_t)SFK + 64) * 4 > ws_size) NK >>= 1;
    const int steps = NS / (NK * 32);   // 8 for NK=64 ... always even

    unsigned short* Bp    = (unsigned short*)d_ws;
    unsigned short* spart = (unsigned short*)((char*)d_ws + bpBytes);
    float*          S     = (float*)((char*)spart + (size_t)NK * SFK * 2);
    float*          fpart = S + SFK;

    ebl_prep<<<(NGRP * CP + 255) / 256, 256, 0, stream>>>(tp, Bp);
    dim3 grid(FKD / MT, NK);
    ebl_gemm<<<grid, 256, 0, stream>>>(mem, Bp, spart, steps);
    ebl_reduce<<<(SFK / 2 + 255) / 256, 256, 0, stream>>>(spart, S, NK);
    ebl_entropy<<<64, 256, 0, stream>>>(S, fpart);
    ebl_finalize<<<1, 64, 0, stream>>>(fpart, out);
}

// Round 6
// 79.692 us; speedup vs baseline: 3.4254x; 3.4254x over previous
//
#include <hip/hip_runtime.h>
#include <hip/hip_bf16.h>

#define NS   16384
#define FKD  2048
#define CD   100
#define CP   112
#define MT   64
#define EPSF 1e-8f
#define SFK  (FKD * CP)          // 229376 elements of one S partial
#define NGRP (NS / 8)            // 2048 k-groups of 8

typedef float f32x4 __attribute__((ext_vector_type(4)));
typedef short bf16x8 __attribute__((ext_vector_type(8)));

__device__ inline unsigned short f2bf(float f) {
    unsigned int u = __float_as_uint(f);
    u += 0x7FFFu + ((u >> 16) & 1u);   // RNE; inputs are finite in [0,1]
    return (unsigned short)(u >> 16);
}

// ---------------- prep: teacher -> bf16 fragment layout ----------------
// Bp[g][c][j] = bf16(tp[(8g+j)*CD + c]) ; col CD == 1.0 (bin-mass column), >CD == 0
__global__ __launch_bounds__(256) void ebl_prep(
    const float* __restrict__ tp, unsigned short* __restrict__ Bp)
{
    const int idx = blockIdx.x * 256 + threadIdx.x;     // (g, c)
    if (idx >= NGRP * CP) return;
    const int g = idx / CP, c = idx - g * CP;
    unsigned short v[8];
    if (c < CD) {
        const float* p = tp + (size_t)g * 8 * CD + c;
        #pragma unroll
        for (int j = 0; j < 8; ++j) v[j] = f2bf(p[(size_t)j * CD]);
    } else {
        const unsigned short fill = (c == CD) ? 0x3F80 : 0;   // bf16(1.0) / 0
        #pragma unroll
        for (int j = 0; j < 8; ++j) v[j] = fill;
    }
    *reinterpret_cast<uint4*>(Bp + (size_t)idx * 8) = *reinterpret_cast<const uint4*>(v);
}

// ---------------- GEMM: barrier-free; round-4 codegen (64 VGPR), NK=64 grid TLP ----------------
// S_partial[kc][m][c] (bf16) = sum over k-chunk of bf16(mem[n][m]) * Bp[n][c]
__global__ __launch_bounds__(256, 4) void ebl_gemm(
    const float* __restrict__ mem, const unsigned short* __restrict__ Bp,
    unsigned short* __restrict__ spart, int steps)
{
    const int t  = threadIdx.x;
    const int w  = t >> 6;                 // wave -> m-subtile
    const int l  = t & 63;
    const int lg = l >> 4, lr = l & 15;
    const int m  = blockIdx.x * MT + w * 16 + lr;
    const int kc = blockIdx.y;
    const int g0 = kc * steps * 4 + lg;    // this lane's first k-group

    const float*          ap = mem + (size_t)g0 * 8 * FKD + m;
    const unsigned short* bp = Bp + ((size_t)g0 * CP + lr) * 8;
    const size_t aStep = (size_t)32 * FKD;   // one k-phase = 32 n-rows
    const size_t bStep = (size_t)4 * CP * 8;

    f32x4 acc[7];
    #pragma unroll
    for (int i = 0; i < 7; ++i) acc[i] = (f32x4){0.f, 0.f, 0.f, 0.f};

    float a0[8], a1[8]; bf16x8 b0[7], b1[7];

#define LOADA(dst, base) { \
    const float* _p = (base); \
    _Pragma("unroll") \
    for (int j = 0; j < 8; ++j) dst[j] = _p[(size_t)j * FKD]; }
#define LOADB(dst, base) { \
    const unsigned short* _q = (base); \
    _Pragma("unroll") \
    for (int nt = 0; nt < 7; ++nt) dst[nt] = *reinterpret_cast<const bf16x8*>(_q + nt * 128); }
#define COMPUTE(aB, bB) { \
    bf16x8 af; \
    _Pragma("unroll") \
    for (int j = 0; j < 8; ++j) af[j] = (short)f2bf(aB[j]); \
    _Pragma("unroll") \
    for (int nt = 0; nt < 7; ++nt) \
        acc[nt] = __builtin_amdgcn_mfma_f32_16x16x32_bf16(af, bB[nt], acc[nt], 0, 0, 0); }

    LOADA(a0, ap);             LOADB(b0, bp);
    LOADA(a1, ap + aStep);     LOADB(b1, bp + bStep);

    // steps is even (8/16/32) by construction
    for (int s = 0; s < steps - 2; s += 2) {
        COMPUTE(a0, b0);
        LOADA(a0, ap + 2 * aStep);  LOADB(b0, bp + 2 * bStep);
        COMPUTE(a1, b1);
        LOADA(a1, ap + 3 * aStep);  LOADB(b1, bp + 3 * bStep);
        ap += 2 * aStep; bp += 2 * bStep;
    }
    COMPUTE(a0, b0);
    COMPUTE(a1, b1);

#undef LOADA
#undef LOADB
#undef COMPUTE

    // C/D layout: col = lane&15, row = (lane>>4)*4 + reg   [verified rounds 1-5]
    unsigned short* sp = spart + (size_t)kc * SFK;
    #pragma unroll
    for (int nt = 0; nt < 7; ++nt) {
        const int c = nt * 16 + lr;
        #pragma unroll
        for (int r = 0; r < 4; ++r) {
            const int mm = blockIdx.x * MT + w * 16 + lg * 4 + r;
            sp[(size_t)mm * CP + c] = f2bf(acc[nt][r]);
        }
    }
}

// ---------------- reduce split-K partials (bf16 -> fp32, parallel) ----------------
__global__ __launch_bounds__(256) void ebl_reduce(
    const unsigned short* __restrict__ spart, float* __restrict__ S, int NK)
{
    const int idx = blockIdx.x * 256 + threadIdx.x;   // uint (2-element) index
    if (idx >= SFK / 2) return;
    float s0 = 0.f, s1 = 0.f;
    for (int p = 0; p < NK; ++p) {
        const unsigned raw = *reinterpret_cast<const unsigned*>(spart + (size_t)p * SFK + (size_t)idx * 2);
        s0 += __uint_as_float(raw << 16);
        s1 += __uint_as_float(raw & 0xFFFF0000u);
    }
    *reinterpret_cast<float2*>(S + (size_t)idx * 2) = make_float2(s0, s1);
}

// ---------------- entropies per f, partial losses ----------------
__global__ __launch_bounds__(256) void ebl_entropy(
    const float* __restrict__ S, float* __restrict__ fpart)
{
    __shared__ float Ss[32 * CP];
    __shared__ float massL[32];
    __shared__ float red[4];
    const int t = threadIdx.x;
    const int f = blockIdx.x;

    for (int idx = t; idx < 32 * CP; idx += 256)
        Ss[idx] = S[(size_t)f * 32 * CP + idx];
    __syncthreads();
    if (t < 32) massL[t] = Ss[t * CP + CD] + EPSF;   // ones-column = bin mass (+EPS)
    __syncthreads();

    float a_int = 0.f, a_mix = 0.f;
    for (int idx = t; idx < 32 * CD; idx += 256) {
        const int k = idx / CD, c = idx - k * CD;
        const float cent = Ss[k * CP + c] / massL[k];
        a_int -= cent * logf(cent + EPSF) * massL[k];
    }
    for (int idx = t; idx < 31 * CD; idx += 256) {
        const int k = idx / CD, c = idx - k * CD;
        const float mix = 0.5f * (Ss[k * CP + c] / massL[k] + Ss[(k + 1) * CP + c] / massL[k + 1]);
        a_mix += mix * logf(mix + EPSF);
    }

    float part = a_int * (1.0f / (float)NS) + 0.5f * a_mix;
    #pragma unroll
    for (int off = 32; off > 0; off >>= 1) part += __shfl_down(part, off);
    if ((t & 63) == 0) red[t >> 6] = part;
    __syncthreads();
    if (t == 0) fpart[f] = (red[0] + red[1]) + (red[2] + red[3]);
}

__global__ void ebl_finalize(const float* __restrict__ fpart, float* __restrict__ out) {
    float v = fpart[threadIdx.x];
    #pragma unroll
    for (int off = 32; off > 0; off >>= 1) v += __shfl_down(v, off);
    if (threadIdx.x == 0) out[0] = v;
}

extern "C" void kernel_launch(void* const* d_in, const int* in_sizes, int n_in,
                              void* d_out, int out_size, void* d_ws, size_t ws_size,
                              hipStream_t stream)
{
    const float* mem = (const float*)d_in[0];
    const float* tp  = (const float*)d_in[1];
    float* out = (float*)d_out;

    const size_t bpBytes = (size_t)NGRP * CP * 8 * 2;    // 3,670,016 B (16-aligned)

    int NK = 64;
    while (NK > 1 &&
           bpBytes + (size_t)NK * SFK * 2 + ((size_t)SFK + 64) * 4 > ws_size) NK >>= 1;
    const int steps = NS / (NK * 32);   // 8 for NK=64 ... always even

    unsigned short* Bp    = (unsigned short*)d_ws;
    unsigned short* spart = (unsigned short*)((char*)d_ws + bpBytes);
    float*          S     = (float*)((char*)spart + (size_t)NK * SFK * 2);
    float*          fpart = S + SFK;

    ebl_prep<<<(NGRP * CP + 255) / 256, 256, 0, stream>>>(tp, Bp);
    dim3 grid(FKD / MT, NK);
    ebl_gemm<<<grid, 256, 0, stream>>>(mem, Bp, spart, steps);
    ebl_reduce<<<(SFK / 2 + 255) / 256, 256, 0, stream>>>(spart, S, NK);
    ebl_entropy<<<64, 256, 0, stream>>>(S, fpart);
    ebl_finalize<<<1, 64, 0, stream>>>(fpart, out);
}

// Round 7
// 79.052 us; speedup vs baseline: 3.4532x; 1.0081x over previous
//
#include <hip/hip_runtime.h>
#include <hip/hip_bf16.h>

#define NS   16384
#define FKD  2048
#define CD   100
#define CP   112
#define MT   64
#define ROWS 64                  // n-rows staged per phase
#define EPSF 1e-8f
#define SFK  (FKD * CP)          // 229376 elements of one S partial
#define NGRP (NS / 8)            // 2048 k-groups of 8

typedef float f32x4 __attribute__((ext_vector_type(4)));
typedef short bf16x8 __attribute__((ext_vector_type(8)));

__device__ inline unsigned short f2bf(float f) {
    unsigned int u = __float_as_uint(f);
    u += 0x7FFFu + ((u >> 16) & 1u);   // RNE; inputs are finite in [0,1]
    return (unsigned short)(u >> 16);
}

__device__ __forceinline__ void gload16(const float* g, float* l) {
    __builtin_amdgcn_global_load_lds(
        (const __attribute__((address_space(1))) void*)g,
        (__attribute__((address_space(3))) void*)l, 16, 0, 0);
}

// ---------------- prep: teacher -> bf16 fragment layout ----------------
// Bp[g][c][j] = bf16(tp[(8g+j)*CD + c]) ; col CD == 1.0 (bin-mass column), >CD == 0
__global__ __launch_bounds__(256) void ebl_prep(
    const float* __restrict__ tp, unsigned short* __restrict__ Bp)
{
    const int idx = blockIdx.x * 256 + threadIdx.x;     // (g, c)
    if (idx >= NGRP * CP) return;
    const int g = idx / CP, c = idx - g * CP;
    unsigned short v[8];
    if (c < CD) {
        const float* p = tp + (size_t)g * 8 * CD + c;
        #pragma unroll
        for (int j = 0; j < 8; ++j) v[j] = f2bf(p[(size_t)j * CD]);
    } else {
        const unsigned short fill = (c == CD) ? 0x3F80 : 0;   // bf16(1.0) / 0
        #pragma unroll
        for (int j = 0; j < 8; ++j) v[j] = fill;
    }
    *reinterpret_cast<uint4*>(Bp + (size_t)idx * 8) = *reinterpret_cast<const uint4*>(v);
}

// ---------------- GEMM: global_load_lds double-buffered A staging (m97 pattern) ----------------
// S_partial[kc][m][c] (bf16) = sum over k-chunk of bf16(mem[n][m]) * Bp[n][c]
__global__ __launch_bounds__(256) void ebl_gemm(
    const float* __restrict__ mem, const unsigned short* __restrict__ Bp,
    unsigned short* __restrict__ spart, int steps)
{
    __shared__ float At[2][ROWS * MT];    // 2 x 16 KB

    const int t  = threadIdx.x;
    const int w  = t >> 6;                 // wave -> m-subtile [w*16, w*16+16)
    const int l  = t & 63;
    const int lg = l >> 4, lr = l & 15;
    const int m0 = blockIdx.x * MT;
    const int kc = blockIdx.y;
    const int n0 = kc * steps * ROWS;      // first n-row of this k-chunk
    const int gb = n0 >> 3;                // first k-group (of 8 rows)

    f32x4 acc[7];
    #pragma unroll
    for (int i = 0; i < 7; ++i) acc[i] = (f32x4){0.f, 0.f, 0.f, 0.f};

    // STAGE: wave w stages rows [w*16, w*16+16) of the phase tile, 4 rows per instr.
    // LDS base is wave-uniform; HW writes lane i -> base + i*16B, which lands
    // lane i=(16r+c) at row (w*16+q*4+r), cols 4c..4c+3 — matching the global src.
#define STAGE(buf, nbase) { \
    const float* gsrc = mem + (size_t)(nbase) * FKD + m0 + (l & 15) * 4; \
    _Pragma("unroll") \
    for (int q = 0; q < 4; ++q) \
        gload16(gsrc + (size_t)(w * 16 + q * 4 + (l >> 4)) * FKD, \
                &At[buf][(w * 16 + q * 4) * MT]); }

    STAGE(0, n0)

    for (int ph = 0; ph < steps; ++ph) {
        const int cur = ph & 1;
        __syncthreads();                       // publishes stage(ph), closes reads of buf cur^1
        if (ph + 1 < steps) STAGE(cur ^ 1, n0 + (ph + 1) * ROWS)

        #pragma unroll
        for (int ks = 0; ks < 2; ++ks) {       // two 32-row MFMA k-steps per phase
            const int g = gb + ph * 8 + ks * 4 + lg;
            const unsigned short* bq = Bp + ((size_t)g * CP + lr) * 8;
            bf16x8 af;
            #pragma unroll
            for (int j = 0; j < 8; ++j)
                af[j] = (short)f2bf(At[cur][(ks * 32 + lg * 8 + j) * MT + w * 16 + lr]);
            #pragma unroll
            for (int nt = 0; nt < 7; ++nt) {
                bf16x8 bf = *reinterpret_cast<const bf16x8*>(bq + nt * 128);
                acc[nt] = __builtin_amdgcn_mfma_f32_16x16x32_bf16(af, bf, acc[nt], 0, 0, 0);
            }
        }
    }
#undef STAGE

    // C/D layout: col = lane&15, row = (lane>>4)*4 + reg   [verified rounds 1-6]
    unsigned short* sp = spart + (size_t)kc * SFK;
    #pragma unroll
    for (int nt = 0; nt < 7; ++nt) {
        const int c = nt * 16 + lr;
        #pragma unroll
        for (int r = 0; r < 4; ++r) {
            const int mm = m0 + w * 16 + lg * 4 + r;
            sp[(size_t)mm * CP + c] = f2bf(acc[nt][r]);
        }
    }
}

// ---------------- reduce split-K partials (bf16 -> fp32, parallel) ----------------
__global__ __launch_bounds__(256) void ebl_reduce(
    const unsigned short* __restrict__ spart, float* __restrict__ S, int NK)
{
    const int idx = blockIdx.x * 256 + threadIdx.x;   // uint (2-element) index
    if (idx >= SFK / 2) return;
    float s0 = 0.f, s1 = 0.f;
    for (int p = 0; p < NK; ++p) {
        const unsigned raw = *reinterpret_cast<const unsigned*>(spart + (size_t)p * SFK + (size_t)idx * 2);
        s0 += __uint_as_float(raw << 16);
        s1 += __uint_as_float(raw & 0xFFFF0000u);
    }
    *reinterpret_cast<float2*>(S + (size_t)idx * 2) = make_float2(s0, s1);
}

// ---------------- entropies per f, partial losses ----------------
__global__ __launch_bounds__(256) void ebl_entropy(
    const float* __restrict__ S, float* __restrict__ fpart)
{
    __shared__ float Ss[32 * CP];
    __shared__ float massL[32];
    __shared__ float red[4];
    const int t = threadIdx.x;
    const int f = blockIdx.x;

    for (int idx = t; idx < 32 * CP; idx += 256)
        Ss[idx] = S[(size_t)f * 32 * CP + idx];
    __syncthreads();
    if (t < 32) massL[t] = Ss[t * CP + CD] + EPSF;   // ones-column = bin mass (+EPS)
    __syncthreads();

    float a_int = 0.f, a_mix = 0.f;
    for (int idx = t; idx < 32 * CD; idx += 256) {
        const int k = idx / CD, c = idx - k * CD;
        const float cent = Ss[k * CP + c] / massL[k];
        a_int -= cent * logf(cent + EPSF) * massL[k];
    }
    for (int idx = t; idx < 31 * CD; idx += 256) {
        const int k = idx / CD, c = idx - k * CD;
        const float mix = 0.5f * (Ss[k * CP + c] / massL[k] + Ss[(k + 1) * CP + c] / massL[k + 1]);
        a_mix += mix * logf(mix + EPSF);
    }

    float part = a_int * (1.0f / (float)NS) + 0.5f * a_mix;
    #pragma unroll
    for (int off = 32; off > 0; off >>= 1) part += __shfl_down(part, off);
    if ((t & 63) == 0) red[t >> 6] = part;
    __syncthreads();
    if (t == 0) fpart[f] = (red[0] + red[1]) + (red[2] + red[3]);
}

__global__ void ebl_finalize(const float* __restrict__ fpart, float* __restrict__ out) {
    float v = fpart[threadIdx.x];
    #pragma unroll
    for (int off = 32; off > 0; off >>= 1) v += __shfl_down(v, off);
    if (threadIdx.x == 0) out[0] = v;
}

extern "C" void kernel_launch(void* const* d_in, const int* in_sizes, int n_in,
                              void* d_out, int out_size, void* d_ws, size_t ws_size,
                              hipStream_t stream)
{
    const float* mem = (const float*)d_in[0];
    const float* tp  = (const float*)d_in[1];
    float* out = (float*)d_out;

    const size_t bpBytes = (size_t)NGRP * CP * 8 * 2;    // 3,670,016 B (16-aligned)

    int NK = 32;
    while (NK > 1 &&
           bpBytes + (size_t)NK * SFK * 2 + ((size_t)SFK + 64) * 4 > ws_size) NK >>= 1;
    const int steps = NS / (NK * ROWS);   // 8 for NK=32

    unsigned short* Bp    = (unsigned short*)d_ws;
    unsigned short* spart = (unsigned short*)((char*)d_ws + bpBytes);
    float*          S     = (float*)((char*)spart + (size_t)NK * SFK * 2);
    float*          fpart = S + SFK;

    ebl_prep<<<(NGRP * CP + 255) / 256, 256, 0, stream>>>(tp, Bp);
    dim3 grid(FKD / MT, NK);
    ebl_gemm<<<grid, 256, 0, stream>>>(mem, Bp, spart, steps);
    ebl_reduce<<<(SFK / 2 + 255) / 256, 256, 0, stream>>>(spart, S, NK);
    ebl_entropy<<<64, 256, 0, stream>>>(S, fpart);
    ebl_finalize<<<1, 64, 0, stream>>>(fpart, out);
}